// Round 3
// baseline (167.197 us; speedup 1.0000x reference)
//
#include <hip/hip_runtime.h>

// LSTM: B=4096, T=256, I=8, H=32, O=1, fp32 in/out, bf16 MFMA compute.
// 256 blocks (1/CU) x 512 threads (8 waves = 2/SIMD for latency hiding).
// Block owns 16 batch rows; wave w owns hidden slice j in {4w+q}.
// Weights sit in the MFMA *first* operand with permuted rows
// (fr -> gate=fr&3, j=4w+(fr>>2)) so each lane's 4 accum regs are the 4
// gates (i,f,g,o) at one (m=lane&15, j=4w+lane>>4): c/h update is fully
// in-register. x-projection zx(t+1)=MFMA(W_ih,x(t+1),bias) is computed one
// step ahead, off the recurrence chain; only MFMA(W_hh,h) is serial.
// h exchanged via double-buffered LDS + ONE raw s_barrier/step with
// LDS-only fences (no vmcnt drain -> depth-2 x prefetch ring stays in
// flight). Weights pre-scaled by log2e so sigmoid/tanh = v_exp + v_rcp.

#define T_LEN 256
#define LOG2E 1.4426950408889634f

typedef __attribute__((ext_vector_type(8))) short bf16x8;
typedef __attribute__((ext_vector_type(4))) float f32x4;

static __device__ inline short f2bf(float f) {
    union { float f; unsigned u; } v; v.f = f;
    unsigned u = v.u;
    unsigned r = (u + 0x7FFFu + ((u >> 16) & 1u)) >> 16;  // RNE
    return (short)r;
}
static __device__ inline float bf2f(short s) {
    union { unsigned u; float f; } v;
    v.u = ((unsigned)(unsigned short)s) << 16;
    return v.f;
}
static __device__ inline float sig_p(float zp) {   // sigmoid, z pre-scaled by log2e
    return __builtin_amdgcn_rcpf(1.f + __builtin_amdgcn_exp2f(-zp));
}
static __device__ inline float tanh_p(float zp) {  // tanh, z pre-scaled by log2e
    return 2.f * __builtin_amdgcn_rcpf(1.f + __builtin_amdgcn_exp2f(-(zp + zp))) - 1.f;
}

__global__ __launch_bounds__(512) void lstm_kernel(
    const float* __restrict__ x, const float* __restrict__ W_ih,
    const float* __restrict__ W_hh, const float* __restrict__ b_ih,
    const float* __restrict__ b_hh, const float* __restrict__ W_out,
    const float* __restrict__ b_out, float* __restrict__ out)
{
    // h double buffer: [buf][m(0..15)][k(0..31)] bf16, row stride 40 shorts
    // (80 B, 16B-aligned b128 reads; m vs m+8 alias 2-way = free)
    __shared__ __attribute__((aligned(16))) short h_lds[2][16 * 40];

    const int tid  = threadIdx.x;
    const int w    = tid >> 6;        // wave 0..7 -> hidden slice {4w..4w+3}
    const int lane = tid & 63;
    const int L    = lane & 15;       // batch row within tile / fragment row
    const int q    = lane >> 4;       // quad
    const int row0 = blockIdx.x * 16;

    // ---- one-time: weight fragments, FIRST-operand layout [row=L][k=q*8+j] ----
    // frag row fr holds W row n = 32*(fr&3) + 4w + (fr>>2)
    const int n = 32 * (L & 3) + 4 * w + (L >> 2);
    bf16x8 whh_f, wih_f = (bf16x8){0,0,0,0,0,0,0,0};
    {
        const float* src = W_hh + n * 32 + q * 8;
#pragma unroll
        for (int j = 0; j < 8; ++j) whh_f[j] = f2bf(src[j] * LOG2E);
        if (q == 0) {                              // only k=0..7 exist (I=8)
            const float* s2 = W_ih + n * 8;
#pragma unroll
            for (int j = 0; j < 8; ++j) wih_f[j] = f2bf(s2[j] * LOG2E);
        }
    }
    // bias in C-layout: reg r -> row fr=4q+r -> n_r = 32r + 4w + q
    f32x4 bias4;
#pragma unroll
    for (int r = 0; r < 4; ++r) {
        const int nr = 32 * r + 4 * w + q;
        bias4[r] = (b_ih[nr] + b_hh[nr]) * LOG2E;
    }

    // zero h(0) buffer
    for (int i = tid; i < 16 * 40; i += 512) h_lds[0][i] = 0;

    // x prefetch ring, depth 2: slot s holds x(2k+s); q==0 lanes only
    const float4* xv = (const float4*)x;
    const size_t xbase = (size_t)(row0 + L) * (T_LEN * 8 / 4);
    float4 xr0[2] = {{0,0,0,0},{0,0,0,0}}, xr1[2] = {{0,0,0,0},{0,0,0,0}};
    if (q == 0) {
        xr0[0] = xv[xbase + 0]; xr1[0] = xv[xbase + 1];
        xr0[1] = xv[xbase + 2]; xr1[1] = xv[xbase + 3];
    }

    float c = 0.f;                     // c at (m=L, j=4w+q)
    const int jme = 4 * w + q;

    // zx(0) = x(0) W_ih^T + bias (off-chain); then refill slot0 with x(2)
    f32x4 zx;
    {
        bf16x8 xf = (bf16x8){0,0,0,0,0,0,0,0};
        if (q == 0) {
            const float4 a = xr0[0], b = xr1[0];
            xf[0] = f2bf(a.x); xf[1] = f2bf(a.y); xf[2] = f2bf(a.z); xf[3] = f2bf(a.w);
            xf[4] = f2bf(b.x); xf[5] = f2bf(b.y); xf[6] = f2bf(b.z); xf[7] = f2bf(b.w);
            xr0[0] = xv[xbase + 4]; xr1[0] = xv[xbase + 5];
        }
        zx = __builtin_amdgcn_mfma_f32_16x16x32_bf16(wih_f, xf, bias4, 0, 0, 0);
    }

    __syncthreads();

#pragma unroll 2
    for (int t = 0; t < T_LEN; ++t) {
        const int par = t & 1;
        // h(t) fragment: [m=L][k=q*8+j]
        bf16x8 hfrag = *(const bf16x8*)(&h_lds[par][L * 40 + q * 8]);

        // the only MFMA on the recurrence chain
        const f32x4 acc = __builtin_amdgcn_mfma_f32_16x16x32_bf16(whh_f, hfrag, zx, 0, 0, 0);

        // off-chain: zx(t+1) from prefetched x(t+1); refill slot with x(t+3)
        {
            const int ns = (t + 1) & 1;
            bf16x8 xf = (bf16x8){0,0,0,0,0,0,0,0};
            if (q == 0) {
                const float4 a = xr0[ns], b = xr1[ns];
                xf[0] = f2bf(a.x); xf[1] = f2bf(a.y); xf[2] = f2bf(a.z); xf[3] = f2bf(a.w);
                xf[4] = f2bf(b.x); xf[5] = f2bf(b.y); xf[6] = f2bf(b.z); xf[7] = f2bf(b.w);
                int tn = t + 3; if (tn >= T_LEN) tn = T_LEN - 1;
                xr0[ns] = xv[xbase + (size_t)tn * 2];
                xr1[ns] = xv[xbase + (size_t)tn * 2 + 1];
            }
            zx = __builtin_amdgcn_mfma_f32_16x16x32_bf16(wih_f, xf, bias4, 0, 0, 0);
        }

        // in-register gates (regs = i,f,g,o) + c/h update
        {
            const float iv = sig_p(acc[0]);
            const float fv = sig_p(acc[1]);
            const float gv = tanh_p(acc[2]);
            const float ov = sig_p(acc[3]);
            c = fmaf(fv, c, iv * gv);
            const float hv = ov * tanh_p(c * LOG2E);
            h_lds[par ^ 1][L * 40 + jme] = f2bf(hv);
        }

        // LDS-only release/acquire around a raw barrier: no vmcnt drain,
        // x prefetch stays in flight across steps.
        __builtin_amdgcn_fence(__ATOMIC_RELEASE, "workgroup", "local");
        __builtin_amdgcn_s_barrier();
        __builtin_amdgcn_fence(__ATOMIC_ACQUIRE, "workgroup", "local");
    }

    // final h = h(T) lives in buf[T&1] = buf[0]
    if (tid < 16) {
        float s = b_out[0];
#pragma unroll
        for (int k = 0; k < 32; ++k) s = fmaf(bf2f(h_lds[0][tid * 40 + k]), W_out[k], s);
        out[row0 + tid] = s;
    }
}

extern "C" void kernel_launch(void* const* d_in, const int* in_sizes, int n_in,
                              void* d_out, int out_size, void* d_ws, size_t ws_size,
                              hipStream_t stream) {
    const float* x     = (const float*)d_in[0];
    const float* W_ih  = (const float*)d_in[1];
    const float* W_hh  = (const float*)d_in[2];
    const float* b_ih  = (const float*)d_in[3];
    const float* b_hh  = (const float*)d_in[4];
    const float* W_out = (const float*)d_in[5];
    const float* b_out = (const float*)d_in[6];
    float* out = (float*)d_out;

    const int B = in_sizes[0] / (T_LEN * 8);  // 4096
    const int tiles = B / 16;                 // 256
    lstm_kernel<<<tiles, 512, 0, stream>>>(x, W_ih, W_hh, b_ih, b_hh, W_out, b_out, out);
}

// Round 4
// 163.435 us; speedup vs baseline: 1.0230x; 1.0230x over previous
//
#include <hip/hip_runtime.h>

// LSTM: B=4096, T=256, I=8, H=32, O=1, fp32 in/out, bf16 MFMA compute.
// 256 blocks (1/CU) x 256 threads (4 waves). Block owns 16 batch rows.
// Wave w owns hidden pair (j = 8q + 2w + e, e=0,1) per lane via the weight-row
// permutation fr -> n = 32*(fr&3) + 8*(fr>>2) + 2w + e  (weights are the MFMA
// FIRST operand), so each lane's accum quad e = gates (i,f,g,o) at
// (m=lane&15, j=8q+2w+e). The two h values are k-adjacent -> one ds_write_b32.
// Step pipeline: MFMA(whh,h,zx) -> act -> write -> barrier -> issue ds_read(h')
// -> [x-frag build + W_ih MFMA + global refill hidden in the read shadow].
// Gate-g weight rows pre-scaled by 2*log2e (others log2e) so activations are
// 5 exp2 + 3 rcp per pair (merged-reciprocal sigmoid*tanh forms).

#define T_LEN 256
#define LOG2E 1.4426950408889634f

typedef short bf16x8 __attribute__((ext_vector_type(8)));
typedef float f32x4 __attribute__((ext_vector_type(4)));

static __device__ inline short f2bf_rne(float f) {          // one-time (weights)
    union { float f; unsigned u; } v; v.f = f;
    unsigned u = v.u;
    return (short)((u + 0x7FFFu + ((u >> 16) & 1u)) >> 16);
}
static __device__ inline short f2bf_fast(float f) {         // round-half-up
    union { float f; unsigned u; } v; v.f = f;
    return (short)((v.u + 0x8000u) >> 16);
}
static __device__ inline unsigned pack_bf2(float a, float b) {
    union { float f; unsigned u; } x, y; x.f = a; y.f = b;
    return ((x.u + 0x8000u) >> 16) | ((y.u + 0x8000u) & 0xFFFF0000u);
}
static __device__ inline float bf2f(short s) {
    union { unsigned u; float f; } v;
    v.u = ((unsigned)(unsigned short)s) << 16;
    return v.f;
}

__global__ __launch_bounds__(256) void lstm_kernel(
    const float* __restrict__ x, const float* __restrict__ W_ih,
    const float* __restrict__ W_hh, const float* __restrict__ b_ih,
    const float* __restrict__ b_hh, const float* __restrict__ W_out,
    const float* __restrict__ b_out, float* __restrict__ out)
{
    // h double buffer: [buf][m(0..15)][k(0..31)] bf16, row stride 40 shorts
    // (80 B; b128 reads and b32 writes alias only 2-way = free)
    __shared__ __attribute__((aligned(16))) short h_lds[2][16 * 40];

    const int tid  = threadIdx.x;
    const int w    = tid >> 6;        // wave 0..3
    const int lane = tid & 63;
    const int L    = lane & 15;       // batch row within tile / A-frag row
    const int q    = lane >> 4;       // quad
    const int row0 = blockIdx.x * 16;

    // ---- one-time: weight fragments (FIRST-operand layout [row=L][k=8q+j]) ----
    // frag e row fr=L holds W row n = 32*(L&3) + 8*(L>>2) + 2w + e,
    // scaled by log2e (gate g rows: 2*log2e, folding tanh's factor 2).
    bf16x8 whh[2], wih[2];
    f32x4  bias[2];
#pragma unroll
    for (int e = 0; e < 2; ++e) {
        const int   n = 32 * (L & 3) + 8 * (L >> 2) + 2 * w + e;
        const float s = ((L & 3) == 2 ? 2.f * LOG2E : LOG2E);
        const float* src = W_hh + n * 32 + q * 8;
        bf16x8 fr;
#pragma unroll
        for (int j = 0; j < 8; ++j) fr[j] = f2bf_rne(src[j] * s);
        whh[e] = fr;
        bf16x8 gr = (bf16x8){0,0,0,0,0,0,0,0};
        if (q == 0) {                              // only k=0..7 exist (I=8)
            const float* s2 = W_ih + n * 8;
#pragma unroll
            for (int j = 0; j < 8; ++j) gr[j] = f2bf_rne(s2[j] * s);
        }
        wih[e] = gr;
        // bias in C-layout: reg r -> row fr=4q+r -> n_r = 32r + 8q + 2w + e
        f32x4 bb;
#pragma unroll
        for (int r = 0; r < 4; ++r) {
            const int   nr = 32 * r + 8 * q + 2 * w + e;
            const float sr = (r == 2 ? 2.f * LOG2E : LOG2E);
            bb[r] = (b_ih[nr] + b_hh[nr]) * sr;
        }
        bias[e] = bb;
    }

    // x ring, depth 2: slot s holds x(t), t === s (mod 2); q==0 lanes only
    const float4* xv = (const float4*)x;
    const size_t  xb = (size_t)(row0 + L) * (T_LEN * 8 / 4);
    float4 xr0[2] = {{0,0,0,0},{0,0,0,0}}, xr1[2] = {{0,0,0,0},{0,0,0,0}};
    bf16x8 xf0 = (bf16x8){0,0,0,0,0,0,0,0};
    if (q == 0) {
        const float4 a = xv[xb + 0], b = xv[xb + 1];      // x(0)
        xf0[0] = f2bf_fast(a.x); xf0[1] = f2bf_fast(a.y);
        xf0[2] = f2bf_fast(a.z); xf0[3] = f2bf_fast(a.w);
        xf0[4] = f2bf_fast(b.x); xf0[5] = f2bf_fast(b.y);
        xf0[6] = f2bf_fast(b.z); xf0[7] = f2bf_fast(b.w);
        xr0[1] = xv[xb + 2]; xr1[1] = xv[xb + 3];          // x(1) -> slot 1
        xr0[0] = xv[xb + 4]; xr1[0] = xv[xb + 5];          // x(2) -> slot 0
    }

    f32x4 zx[2];
    zx[0] = __builtin_amdgcn_mfma_f32_16x16x32_bf16(wih[0], xf0, bias[0], 0, 0, 0);
    zx[1] = __builtin_amdgcn_mfma_f32_16x16x32_bf16(wih[1], xf0, bias[1], 0, 0, 0);

    bf16x8 hfrag = (bf16x8){0,0,0,0,0,0,0,0};              // h(0) = 0
    float c0 = 0.f, c1 = 0.f;

#pragma unroll 2
    for (int t = 0; t < T_LEN; ++t) {
        const int nxt = (t + 1) & 1;

        // the only MFMAs on the recurrence chain
        const f32x4 a0 = __builtin_amdgcn_mfma_f32_16x16x32_bf16(whh[0], hfrag, zx[0], 0, 0, 0);
        const f32x4 a1 = __builtin_amdgcn_mfma_f32_16x16x32_bf16(whh[1], hfrag, zx[1], 0, 0, 0);

        // activations: regs r = (i, f, g2, o); g rows pre-doubled.
        // sig(a)*tanh(b) = (1-eb)*rcp((1+ea)(1+eb)); args clamped for NaN-safety
        float h0, h1;
        {
            const float ei = __builtin_amdgcn_exp2f(fminf(-a0[0], 40.f));
            const float ef = __builtin_amdgcn_exp2f(fminf(-a0[1], 40.f));
            const float eg = __builtin_amdgcn_exp2f(fminf(-a0[2], 40.f));
            const float eo = __builtin_amdgcn_exp2f(fminf(-a0[3], 40.f));
            const float fv = __builtin_amdgcn_rcpf(1.f + ef);
            const float ig = (1.f - eg) * __builtin_amdgcn_rcpf((1.f + ei) * (1.f + eg));
            c0 = fmaf(fv, c0, ig);
            const float ec = __builtin_amdgcn_exp2f(fminf(c0 * (-2.f * LOG2E), 40.f));
            h0 = (1.f - ec) * __builtin_amdgcn_rcpf((1.f + eo) * (1.f + ec));
        }
        {
            const float ei = __builtin_amdgcn_exp2f(fminf(-a1[0], 40.f));
            const float ef = __builtin_amdgcn_exp2f(fminf(-a1[1], 40.f));
            const float eg = __builtin_amdgcn_exp2f(fminf(-a1[2], 40.f));
            const float eo = __builtin_amdgcn_exp2f(fminf(-a1[3], 40.f));
            const float fv = __builtin_amdgcn_rcpf(1.f + ef);
            const float ig = (1.f - eg) * __builtin_amdgcn_rcpf((1.f + ei) * (1.f + eg));
            c1 = fmaf(fv, c1, ig);
            const float ec = __builtin_amdgcn_exp2f(fminf(c1 * (-2.f * LOG2E), 40.f));
            h1 = (1.f - ec) * __builtin_amdgcn_rcpf((1.f + eo) * (1.f + ec));
        }

        // h(t+1) at (m=L, j=8q+2w / +1): adjacent -> single b32 store
        *(unsigned*)(&h_lds[nxt][L * 40 + 8 * q + 2 * w]) = pack_bf2(h0, h1);

        __builtin_amdgcn_fence(__ATOMIC_RELEASE, "workgroup", "local");
        __builtin_amdgcn_s_barrier();
        __builtin_amdgcn_fence(__ATOMIC_ACQUIRE, "workgroup", "local");

        // issue h(t+1) read; hide the whole x-path in its ~120-cyc shadow
        hfrag = *(const bf16x8*)(&h_lds[nxt][L * 40 + q * 8]);

        {   // xfrag(t+1) from ring (q>0 lanes hold zeros; their B-rows multiply
            // the zero k>=8 rows of wih -> contribute nothing, no branch needed)
            const float4 a = xr0[nxt], b = xr1[nxt];
            bf16x8 xf;
            xf[0] = f2bf_fast(a.x); xf[1] = f2bf_fast(a.y);
            xf[2] = f2bf_fast(a.z); xf[3] = f2bf_fast(a.w);
            xf[4] = f2bf_fast(b.x); xf[5] = f2bf_fast(b.y);
            xf[6] = f2bf_fast(b.z); xf[7] = f2bf_fast(b.w);
            zx[0] = __builtin_amdgcn_mfma_f32_16x16x32_bf16(wih[0], xf, bias[0], 0, 0, 0);
            zx[1] = __builtin_amdgcn_mfma_f32_16x16x32_bf16(wih[1], xf, bias[1], 0, 0, 0);
            if (q == 0) {                      // refill slot with x(t+3)
                int tn = t + 3; if (tn >= T_LEN) tn = T_LEN - 1;
                xr0[nxt] = xv[xb + (size_t)tn * 2];
                xr1[nxt] = xv[xb + (size_t)tn * 2 + 1];
            }
        }
    }

    // h(T) lives in buf[(255+1)&1] = buf[0]
    if (tid < 16) {
        float s = b_out[0];
#pragma unroll
        for (int k = 0; k < 32; ++k) s = fmaf(bf2f(h_lds[0][tid * 40 + k]), W_out[k], s);
        out[row0 + tid] = s;
    }
}

extern "C" void kernel_launch(void* const* d_in, const int* in_sizes, int n_in,
                              void* d_out, int out_size, void* d_ws, size_t ws_size,
                              hipStream_t stream) {
    const float* x     = (const float*)d_in[0];
    const float* W_ih  = (const float*)d_in[1];
    const float* W_hh  = (const float*)d_in[2];
    const float* b_ih  = (const float*)d_in[3];
    const float* b_hh  = (const float*)d_in[4];
    const float* W_out = (const float*)d_in[5];
    const float* b_out = (const float*)d_in[6];
    float* out = (float*)d_out;

    const int B = in_sizes[0] / (T_LEN * 8);  // 4096
    const int tiles = B / 16;                 // 256
    lstm_kernel<<<tiles, 256, 0, stream>>>(x, W_ih, W_hh, b_ih, b_hh, W_out, b_out, out);
}

// Round 5
// 147.819 us; speedup vs baseline: 1.1311x; 1.1056x over previous
//
#include <hip/hip_runtime.h>

// LSTM: B=4096, T=256, I=8, H=32, O=1, fp32 in/out, bf16 MFMA compute.
// 256 blocks (1/CU) x 256 threads (4 waves). Block owns 16 batch rows.
// Wave w owns hidden pair (j = 8q + 2w + e) per lane via weight-row
// permutation fr -> n = 32*(fr&3) + 8*(fr>>2) + 2w + e (weights are the MFMA
// FIRST operand), so each lane's accum quad e = gates (i,f,g,o) at
// (m=lane&15, j=8q+2w+e). c/h update fully in-register; h exchanged via
// double-buffered LDS, one __syncthreads()/step.
// KEY CHANGE (R5): x is staged into LDS as bf16 in two 128-step chunks, so
// the steady-state loop has ZERO global memory ops -> the barrier's implicit
// s_waitcnt drains only lgkmcnt (cheap), never an in-flight HBM load. The
// per-step ~500-cyc vmcnt drain at the fence (R2-R4's hidden tax) is gone.
// Gate-g rows pre-scaled by 2*log2e (others log2e): 5 exp2 + 3 rcp per pair.

#define T_LEN   256
#define HALF_T  128
#define XSTRIDE 130   // shorts per timestep row (16 L x 8 bf16 + 2 pad)
#define LOG2E   1.4426950408889634f

typedef short bf16x8 __attribute__((ext_vector_type(8)));
typedef float f32x4  __attribute__((ext_vector_type(4)));
typedef unsigned u32x4 __attribute__((ext_vector_type(4)));

static __device__ inline short f2bf_rne(float f) {          // one-time (weights)
    union { float f; unsigned u; } v; v.f = f;
    unsigned u = v.u;
    return (short)((u + 0x7FFFu + ((u >> 16) & 1u)) >> 16);
}
static __device__ inline unsigned pack_bf2(float a, float b) {  // low=a, high=b
    union { float f; unsigned u; } x, y; x.f = a; y.f = b;
    return ((x.u + 0x8000u) >> 16) | ((y.u + 0x8000u) & 0xFFFF0000u);
}
static __device__ inline float bf2f(short s) {
    union { unsigned u; float f; } v;
    v.u = ((unsigned)(unsigned short)s) << 16;
    return v.f;
}

__global__ __launch_bounds__(256) void lstm_kernel(
    const float* __restrict__ x, const float* __restrict__ W_ih,
    const float* __restrict__ W_hh, const float* __restrict__ b_ih,
    const float* __restrict__ b_hh, const float* __restrict__ W_out,
    const float* __restrict__ b_out, float* __restrict__ out)
{
    // x chunk: [t_local(0..127)][L(0..15)][8] bf16, stride 130 shorts/t
    // (bank = (t + 4L) & 31 -> conflict-free staging writes and loop reads)
    __shared__ __attribute__((aligned(16))) short xl[HALF_T * XSTRIDE];
    // h double buffer: [buf][m(0..15)][k(0..31)] bf16, row stride 40 shorts
    __shared__ __attribute__((aligned(16))) short h_lds[2][16 * 40];

    const int tid  = threadIdx.x;
    const int w    = tid >> 6;        // wave 0..3
    const int lane = tid & 63;
    const int L    = lane & 15;       // batch row within tile / frag row
    const int q    = lane >> 4;       // quad
    const int row0 = blockIdx.x * 16;
    const float4* xv = (const float4*)x;

    // ---- one-time: weight fragments (FIRST-operand layout [row=L][k=8q+j]) ----
    // frag e row fr=L holds W row n = 32*(L&3) + 8*(L>>2) + 2w + e,
    // scaled by log2e (gate-g rows: 2*log2e, folding tanh's factor 2).
    bf16x8 whh[2], wih[2];
    f32x4  bias[2];
#pragma unroll
    for (int e = 0; e < 2; ++e) {
        const int   n = 32 * (L & 3) + 8 * (L >> 2) + 2 * w + e;
        const float s = ((L & 3) == 2 ? 2.f * LOG2E : LOG2E);
        const float* src = W_hh + n * 32 + q * 8;
        bf16x8 fr;
#pragma unroll
        for (int j = 0; j < 8; ++j) fr[j] = f2bf_rne(src[j] * s);
        whh[e] = fr;
        bf16x8 gr = (bf16x8){0,0,0,0,0,0,0,0};
        if (q == 0) {                              // only k=0..7 exist (I=8)
            const float* s2 = W_ih + n * 8;
#pragma unroll
            for (int j = 0; j < 8; ++j) gr[j] = f2bf_rne(s2[j] * s);
        }
        wih[e] = gr;
        // bias in C-layout: reg r -> row fr=4q+r -> n_r = 32r + 8q + 2w + e
        f32x4 bb;
#pragma unroll
        for (int r = 0; r < 4; ++r) {
            const int   nr = 32 * r + 8 * q + 2 * w + e;
            const float sr = (r == 2 ? 2.f * LOG2E : LOG2E);
            bb[r] = (b_ih[nr] + b_hh[nr]) * sr;
        }
        bias[e] = bb;
    }

    // zero h(0) buffer
    for (int i = tid; i < 16 * 40; i += 256) h_lds[0][i] = 0;

    // ---- stage chunk 0 (t in [0,128)) into xl ----
    // idx = tid + 256*it: L2 = idx>>7, tl = idx&127. Global reads: lane-
    // consecutive tl -> contiguous 32B/lane. LDS write bank = (tl+4*L2)&31.
#pragma unroll
    for (int it = 0; it < 8; ++it) {
        const int idx = tid + (it << 8);
        const int L2  = idx >> 7;
        const int tl  = idx & (HALF_T - 1);
        const float4* srcp = xv + ((size_t)(row0 + L2) * T_LEN + tl) * 2;
        const float4 a = srcp[0], b = srcp[1];
        u32x4 u;
        u[0] = pack_bf2(a.x, a.y); u[1] = pack_bf2(a.z, a.w);
        u[2] = pack_bf2(b.x, b.y); u[3] = pack_bf2(b.z, b.w);
        *(u32x4*)(&xl[tl * XSTRIDE + L2 * 8]) = u;
    }
    __syncthreads();

    // zx(0) from x(0)
    f32x4 zx[2];
    {
        const bf16x8 xf0 = *(const bf16x8*)(&xl[L * 8]);
        zx[0] = __builtin_amdgcn_mfma_f32_16x16x32_bf16(wih[0], xf0, bias[0], 0, 0, 0);
        zx[1] = __builtin_amdgcn_mfma_f32_16x16x32_bf16(wih[1], xf0, bias[1], 0, 0, 0);
    }

    float c0 = 0.f, c1 = 0.f;

#pragma unroll 2
    for (int t = 0; t < T_LEN; ++t) {
        if (t == HALF_T - 1) {
            // all chunk-0 reads finished (last was x(127) in iter 126, before
            // iter 126's end barrier). Re-stage t in [128,256).
#pragma unroll
            for (int it = 0; it < 8; ++it) {
                const int idx = tid + (it << 8);
                const int L2  = idx >> 7;
                const int tl  = idx & (HALF_T - 1);
                const float4* srcp = xv + ((size_t)(row0 + L2) * T_LEN + HALF_T + tl) * 2;
                const float4 a = srcp[0], b = srcp[1];
                u32x4 u;
                u[0] = pack_bf2(a.x, a.y); u[1] = pack_bf2(a.z, a.w);
                u[2] = pack_bf2(b.x, b.y); u[3] = pack_bf2(b.z, b.w);
                *(u32x4*)(&xl[tl * XSTRIDE + L2 * 8]) = u;
            }
            __syncthreads();   // after this, no vm ops outstanding again
        }

        const int par = t & 1, nxt = par ^ 1;

        // h(t) fragment [m=L][k=8q+j]
        const bf16x8 hfrag = *(const bf16x8*)(&h_lds[par][L * 40 + q * 8]);
        // x(t+1) fragment straight from LDS (all quads broadcast-read the same
        // 16 addresses; q>0 lanes multiply zeroed wih rows -> contribute 0)
        int tn = t + 1; if (tn >= T_LEN) tn = T_LEN - 1;
        const bf16x8 xfrag = *(const bf16x8*)(&xl[(tn & (HALF_T - 1)) * XSTRIDE + L * 8]);

        // recurrence MFMAs (chain) + next-step zx (off-chain)
        const f32x4 a0 = __builtin_amdgcn_mfma_f32_16x16x32_bf16(whh[0], hfrag, zx[0], 0, 0, 0);
        const f32x4 a1 = __builtin_amdgcn_mfma_f32_16x16x32_bf16(whh[1], hfrag, zx[1], 0, 0, 0);
        zx[0] = __builtin_amdgcn_mfma_f32_16x16x32_bf16(wih[0], xfrag, bias[0], 0, 0, 0);
        zx[1] = __builtin_amdgcn_mfma_f32_16x16x32_bf16(wih[1], xfrag, bias[1], 0, 0, 0);

        // activations: regs r = (i, f, g2, o); g rows pre-doubled.
        // sig(a)*tanh(b) = (1-eb)*rcp((1+ea)(1+eb)); c-exp clamped (|c| can grow)
        float h0, h1;
        {
            const float ei = __builtin_amdgcn_exp2f(-a0[0]);
            const float ef = __builtin_amdgcn_exp2f(-a0[1]);
            const float eg = __builtin_amdgcn_exp2f(-a0[2]);
            const float eo = __builtin_amdgcn_exp2f(-a0[3]);
            const float fv = __builtin_amdgcn_rcpf(1.f + ef);
            const float ig = (1.f - eg) * __builtin_amdgcn_rcpf((1.f + ei) * (1.f + eg));
            c0 = fmaf(fv, c0, ig);
            const float ec = __builtin_amdgcn_exp2f(fminf(c0 * (-2.f * LOG2E), 40.f));
            h0 = (1.f - ec) * __builtin_amdgcn_rcpf((1.f + eo) * (1.f + ec));
        }
        {
            const float ei = __builtin_amdgcn_exp2f(-a1[0]);
            const float ef = __builtin_amdgcn_exp2f(-a1[1]);
            const float eg = __builtin_amdgcn_exp2f(-a1[2]);
            const float eo = __builtin_amdgcn_exp2f(-a1[3]);
            const float fv = __builtin_amdgcn_rcpf(1.f + ef);
            const float ig = (1.f - eg) * __builtin_amdgcn_rcpf((1.f + ei) * (1.f + eg));
            c1 = fmaf(fv, c1, ig);
            const float ec = __builtin_amdgcn_exp2f(fminf(c1 * (-2.f * LOG2E), 40.f));
            h1 = (1.f - ec) * __builtin_amdgcn_rcpf((1.f + eo) * (1.f + ec));
        }

        // h(t+1) at (m=L, j=8q+2w / +1): adjacent -> single b32 store
        *(unsigned*)(&h_lds[nxt][L * 40 + 8 * q + 2 * w]) = pack_bf2(h0, h1);

        __syncthreads();   // LDS-only drain: no global ops in flight
    }

    // h(T) lives in buf[(255+1)&1] = buf[0]
    if (tid < 16) {
        float s = b_out[0];
#pragma unroll
        for (int k = 0; k < 32; ++k) s = fmaf(bf2f(h_lds[0][tid * 40 + k]), W_out[k], s);
        out[row0 + tid] = s;
    }
}

extern "C" void kernel_launch(void* const* d_in, const int* in_sizes, int n_in,
                              void* d_out, int out_size, void* d_ws, size_t ws_size,
                              hipStream_t stream) {
    const float* x     = (const float*)d_in[0];
    const float* W_ih  = (const float*)d_in[1];
    const float* W_hh  = (const float*)d_in[2];
    const float* b_ih  = (const float*)d_in[3];
    const float* b_hh  = (const float*)d_in[4];
    const float* W_out = (const float*)d_in[5];
    const float* b_out = (const float*)d_in[6];
    float* out = (float*)d_out;

    const int B = in_sizes[0] / (T_LEN * 8);  // 4096
    const int tiles = B / 16;                 // 256
    lstm_kernel<<<tiles, 256, 0, stream>>>(x, W_ih, W_hh, b_ih, b_hh, W_out, b_out, out);
}